// Round 1
// baseline (582.901 us; speedup 1.0000x reference)
//
#include <hip/hip_runtime.h>

// SpikeFP64ScaleBy2K: each row of x,k (64 floats of 0.0/1.0) is a fp64 bit
// pattern, big-endian (index 0 = sign bit = fp64 bit 63). Reference computes
// x with exponent e_x + int(k) (k decoded from its own fp64 fields), mod 2048,
// passthrough when k == +/-0. All {0,1}-float arithmetic is exact, so integer
// bit ops reproduce it bit-for-bit.
//
// One wave (64 lanes) per row: lane i loads element i (coalesced), __ballot
// packs the row into a 64-bit mask, bitreverse gives the IEEE bit pattern.

__global__ __launch_bounds__(256) void spike_fp64_scale_kernel(
    const float* __restrict__ x,
    const float* __restrict__ k,
    float* __restrict__ out,
    int nrows)
{
    const int gid  = blockIdx.x * blockDim.x + threadIdx.x;
    const int row  = gid >> 6;           // one wave per row
    const int lane = threadIdx.x & 63;
    if (row >= nrows) return;

    const size_t base = (size_t)row * 64 + lane;
    const float xf = x[base];
    const float kf = k[base];

    // bit lane of mask = element[lane]; reverse so bit b = fp64 bit b.
    const unsigned long long mx = __ballot(xf != 0.0f);
    const unsigned long long mk = __ballot(kf != 0.0f);
    const unsigned long long ux = __builtin_bitreverse64(mx);
    const unsigned long long uk = __builtin_bitreverse64(mk);

    // e_k = biased exponent of k (11 bits). shift = (e_k - 1023) mod 2048;
    // only low 4 bits used: (e_k - 1023) mod 16 == (e_k + 1) & 15.
    const unsigned ek = (unsigned)(uk >> 52) & 0x7FFu;
    const unsigned sh = (ek + 1u) & 15u;

    // val16 = [1, top-15 mantissa bits of k] as 16-bit int (implicit leading 1)
    const unsigned val16 = (1u << 15) | ((unsigned)(uk >> 37) & 0x7FFFu);

    // barrel shift right by (15 - sh), keep low 11 bits -> |k| as integer
    const unsigned kabs = (val16 >> (15u - sh)) & 0x7FFu;

    // two's complement negate (11-bit) if sign of k set
    const unsigned kfin = (uk >> 63) ? ((0u - kabs) & 0x7FFu) : kabs;

    // new exponent = e_x + kfin mod 2048
    const unsigned ex   = (unsigned)(ux >> 52) & 0x7FFu;
    const unsigned enew = (ex + kfin) & 0x7FFu;

    // k == +/-0 (all bits except sign zero) -> passthrough x
    const bool kzero = (uk & 0x7FFFFFFFFFFFFFFFull) == 0ull;
    const unsigned long long uscaled =
        (ux & ~(0x7FFull << 52)) | ((unsigned long long)enew << 52);
    const unsigned long long uout = kzero ? ux : uscaled;

    // lane i writes big-endian bit i = fp64 bit (63 - i), as 0.0f/1.0f
    out[base] = (float)((uout >> (63 - lane)) & 1ull);
}

extern "C" void kernel_launch(void* const* d_in, const int* in_sizes, int n_in,
                              void* d_out, int out_size, void* d_ws, size_t ws_size,
                              hipStream_t stream) {
    const float* x = (const float*)d_in[0];
    const float* k = (const float*)d_in[1];
    float* out = (float*)d_out;

    const int nrows = in_sizes[0] / 64;      // N = 1048576
    const int threads = 256;                 // 4 waves/block, 1 row/wave
    const int total_threads = nrows * 64;
    const int blocks = (total_threads + threads - 1) / threads;

    spike_fp64_scale_kernel<<<blocks, threads, 0, stream>>>(x, k, out, nrows);
}

// Round 2
// 570.816 us; speedup vs baseline: 1.0212x; 1.0212x over previous
//
#include <hip/hip_runtime.h>

// SpikeFP64ScaleBy2K: each row of x,k (64 floats of 0.0/1.0) is a fp64 bit
// pattern, big-endian (element 0 = fp64 bit 63). out = x with exponent
// (e_x + int(k)) mod 2048, passthrough when k == +/-0. Integer bit ops
// reproduce the {0,1}-float reference exactly (absmax 0, verified R1).
//
// R2: 16 B/lane vectorization. One wave = 4 rows; lane = (g = row-in-wave,
// j = float4-within-row). Per-lane nibble pack -> reversed-nibble placed at
// fp64 bit position -> OR-reduce over the 16-lane group via __shfl_xor.

__device__ __forceinline__ unsigned long long shfl_xor_u64(unsigned long long v, int m) {
    unsigned lo = (unsigned)v;
    unsigned hi = (unsigned)(v >> 32);
    lo = (unsigned)__shfl_xor((int)lo, m, 64);
    hi = (unsigned)__shfl_xor((int)hi, m, 64);
    return ((unsigned long long)hi << 32) | lo;
}

__global__ __launch_bounds__(256) void spike_fp64_scale_kernel(
    const float4* __restrict__ x4,
    const float4* __restrict__ k4,
    float4* __restrict__ o4,
    int nrows)
{
    const int wid  = (blockIdx.x * blockDim.x + threadIdx.x) >> 6;  // global wave
    const int lane = threadIdx.x & 63;
    const int g    = lane >> 4;          // row within wave (0..3)
    const int j    = lane & 15;          // float4 index within row (0..15)
    const int row  = wid * 4 + g;
    if (row >= nrows) return;

    const size_t idx = (size_t)row * 16 + j;   // wave covers 1024 contiguous B
    const float4 xv = x4[idx];
    const float4 kv = k4[idx];

    // nibble: bit b = (element 4j+b != 0)
    const unsigned nx = (xv.x != 0.0f ? 1u : 0u) | (xv.y != 0.0f ? 2u : 0u)
                      | (xv.z != 0.0f ? 4u : 0u) | (xv.w != 0.0f ? 8u : 0u);
    const unsigned nk = (kv.x != 0.0f ? 1u : 0u) | (kv.y != 0.0f ? 2u : 0u)
                      | (kv.z != 0.0f ? 4u : 0u) | (kv.w != 0.0f ? 8u : 0u);

    // 4-bit reverse LUT packed in a 64-bit constant (nibble n at position n).
    const unsigned long long REV4 = 0xF7B3D591E6A2C480ull;
    const int sh = 60 - 4 * j;  // element 4j+b sits at fp64 bit 63-4j-b
    unsigned long long ux = ((REV4 >> (nx * 4)) & 0xFull) << sh;
    unsigned long long uk = ((REV4 >> (nk * 4)) & 0xFull) << sh;

    // OR-reduce across the 16-lane group (xor masks 1,2,4,8 stay in-group)
    #pragma unroll
    for (int m = 1; m <= 8; m <<= 1) {
        ux |= shfl_xor_u64(ux, m);
        uk |= shfl_xor_u64(uk, m);
    }

    // ---- scalar fp64-field logic (verified exact in R1) ----
    const unsigned ek = (unsigned)(uk >> 52) & 0x7FFu;
    const unsigned shv = (ek + 1u) & 15u;                       // (e_k-1023) & 15
    const unsigned val16 = (1u << 15) | ((unsigned)(uk >> 37) & 0x7FFFu);
    const unsigned kabs = (val16 >> (15u - shv)) & 0x7FFu;      // |k| as integer
    const unsigned kfin = (uk >> 63) ? ((0u - kabs) & 0x7FFu) : kabs;
    const unsigned ex   = (unsigned)(ux >> 52) & 0x7FFu;
    const unsigned enew = (ex + kfin) & 0x7FFu;
    const bool kzero = (uk & 0x7FFFFFFFFFFFFFFFull) == 0ull;
    const unsigned long long uscaled =
        (ux & ~(0x7FFull << 52)) | ((unsigned long long)enew << 52);
    const unsigned long long uout = kzero ? ux : uscaled;

    // epilogue: reversed nibble at our position -> 4 big-endian elements
    const unsigned nout = (unsigned)((uout >> sh) & 0xFull);
    float4 o;
    o.x = (float)((nout >> 3) & 1u);
    o.y = (float)((nout >> 2) & 1u);
    o.z = (float)((nout >> 1) & 1u);
    o.w = (float)( nout       & 1u);
    o4[idx] = o;
}

extern "C" void kernel_launch(void* const* d_in, const int* in_sizes, int n_in,
                              void* d_out, int out_size, void* d_ws, size_t ws_size,
                              hipStream_t stream) {
    const float4* x4 = (const float4*)d_in[0];
    const float4* k4 = (const float4*)d_in[1];
    float4* o4 = (float4*)d_out;

    const int nrows = in_sizes[0] / 64;          // N = 1048576
    const int total_threads = nrows * 16;        // 16 lanes per row
    const int threads = 256;
    const int blocks = (total_threads + threads - 1) / threads;

    spike_fp64_scale_kernel<<<blocks, threads, 0, stream>>>(x4, k4, o4, nrows);
}